// Round 8
// baseline (48.773 us; speedup 1.0000x reference)
//
#include <hip/hip_runtime.h>
#include <math.h>

typedef __attribute__((ext_vector_type(8))) __bf16 bf16x8;
typedef __attribute__((ext_vector_type(4))) __bf16 bf16x4;
typedef __attribute__((ext_vector_type(4))) float f32x4;

#define PLANE 16384
#define ROWW 128

// ws float layout:
//   [0, 12288)     kern [b][c][12]  (taps 0..8 + pad, f4-aligned)
//   [12288, 13312) att  [b][128]
//   [13312, 21504) wfrag: 16384 ushorts (bf16). B-operand fragments of conv_w^T:
//                  frag[ot(8)][kc(4)][lane(64)][j(8)] = conv_w[ot*16+(lane&15)][kc*32+8*(lane>>4)+j]

__global__ __launch_bounds__(256) void precompute_kernel(
    const float* __restrict__ altitude,
    const float* __restrict__ W1,
    const float* __restrict__ W2,
    const float* __restrict__ ca_w1,
    const float* __restrict__ ca_w2,
    const float* __restrict__ conv_w,
    float* __restrict__ ws)
{
    int bid = blockIdx.x;
    int b = bid >> 2;          // image
    int q = bid & 3;           // quarter of the kern work
    int t = threadIdx.x;
    __shared__ float alt_s[128];
    __shared__ float feat_s[128];
    __shared__ float a1_s[16];

    if (t < 128) alt_s[t] = altitude[b * 128 + t];
    __syncthreads();

    if (t < 128) {
        float s = 0.f;
        const float* wrow = W1 + t * 128;
        for (int j = 0; j < 128; ++j) s += alt_s[j] * wrow[j];
        feat_s[t] = (s >= 0.f) ? s : 0.1f * s;
    } else if (t < 144 && q == 1) {
        int r = t - 128;
        float s = 0.f;
        const float* wrow = ca_w1 + r * 128;
        for (int j = 0; j < 128; ++j) s += alt_s[j] * wrow[j];
        a1_s[r] = (s >= 0.f) ? s : 0.1f * s;
    }
    __syncthreads();

    // this quarter's slice of the 1152 generated-kernel dots -> [b][c][12]
    for (int i = t; i < 288; i += 256) {
        int m = q * 288 + i;
        float s = 0.f;
        const float* wrow = W2 + m * 128;
        for (int j = 0; j < 128; ++j) s += feat_s[j] * wrow[j];
        int c = m / 9, k = m % 9;
        ws[b * 1536 + c * 12 + k] = s;
    }
    if (q == 1 && t < 128) {
        float s = 0.f;
        const float* wrow = ca_w2 + t * 16;
        for (int r = 0; r < 16; ++r) s += a1_s[r] * wrow[r];
        ws[12288 + b * 128 + t] = 1.f / (1.f + expf(-s));
    }
    if (q == 2 && t < 256) {
        int kc   = t >> 6;
        int lane = t & 63;
        int o  = b * 16 + (lane & 15);
        int cb = kc * 32 + 8 * (lane >> 4);
        bf16x8 v;
        #pragma unroll
        for (int j = 0; j < 8; ++j)
            v[j] = (__bf16)conv_w[o * 128 + cb + j];
        ushort* wf = (ushort*)(ws + 13312);
        *reinterpret_cast<bf16x8*>(wf + ((size_t)(b * 4 + kc) * 64 + lane) * 8) = v;
    }
}

__global__ __launch_bounds__(512, 8) void fused_kernel(
    const float* __restrict__ x,
    const float* __restrict__ conv_b,
    const float* __restrict__ ws,
    float* __restrict__ out)
{
    const float* __restrict__ kern_w = ws;
    const float* __restrict__ att_w  = ws + 12288;
    const ushort* __restrict__ wfrag = (const ushort*)(ws + 13312);

    int bid = blockIdx.x;
    int b = bid & 7;          // XCD swizzle: each XCD streams one batch image
    int h = bid >> 3;         // row 0..127

    // dwT[px][c] bf16, 128 px, row stride 136 ushorts.
    // c organized in 16 vblocks of 8 ch; vblock v lives at slot (v ^ (px>>3)).
    __shared__ __align__(16) ushort dwT[128 * 136];
    __shared__ __align__(16) float ktaps[128 * 12];   // [c][12] taps

    int t = threadIdx.x;
    const float* __restrict__ xb = x + (size_t)b * 128 * PLANE;

    // stage taps into LDS: 384 float4s
    for (int i = t; i < 384; i += 512) {
        float4 v = *(const float4*)(kern_w + b * 1536 + i * 4);
        *(float4*)(&ktaps[i * 4]) = v;
    }
    __syncthreads();

    // ---------------- Phase 1: depthwise 3x3 + ReLU -> dwT (bf16) ----------------
    {
        int pg = t & 15;           // 8-px group: px = pg*8 .. pg*8+7 (full 128-px row)
        int cg = t >> 4;           // 4-ch group: c = cg*4 .. cg*4+3  (cg 0..31)
        int gp0 = pg * 8;
        int c0 = cg * 4;

        int   rT = (h > 0)   ? h - 1 : h;
        int   rB = (h < 127) ? h + 1 : h;
        float mT = (h > 0)   ? 1.f : 0.f;
        float mB = (h < 127) ? 1.f : 0.f;
        float mL = (pg > 0)  ? 1.f : 0.f;   // image left edge
        float mR = (pg < 15) ? 1.f : 0.f;   // image right edge

        bf16x4 bv0, bv1, bv2, bv3, bv4, bv5, bv6, bv7;  // [px j] -> 4 bf16 along c

#define ROWACC(A, B, KL, KC, KR) {                                     \
        float l_ = __shfl_up((B).w, 1) * mL;                           \
        float r_ = __shfl_down((A).x, 1) * mR;                         \
        o0 = fmaf((KL), l_,    fmaf((KC), (A).x, fmaf((KR), (A).y, o0))); \
        o1 = fmaf((KL), (A).x, fmaf((KC), (A).y, fmaf((KR), (A).z, o1))); \
        o2 = fmaf((KL), (A).y, fmaf((KC), (A).z, fmaf((KR), (A).w, o2))); \
        o3 = fmaf((KL), (A).z, fmaf((KC), (A).w, fmaf((KR), (B).x, o3))); \
        o4 = fmaf((KL), (A).w, fmaf((KC), (B).x, fmaf((KR), (B).y, o4))); \
        o5 = fmaf((KL), (B).x, fmaf((KC), (B).y, fmaf((KR), (B).z, o5))); \
        o6 = fmaf((KL), (B).y, fmaf((KC), (B).z, fmaf((KR), (B).w, o6))); \
        o7 = fmaf((KL), (B).z, fmaf((KC), (B).w, fmaf((KR), r_,    o7))); }

#define DW_CH(CI) {                                                    \
        const float* q_ = xb + (size_t)(c0 + (CI)) * PLANE;            \
        const float* pT = q_ + rT * ROWW + gp0;                        \
        const float* pC = q_ + h  * ROWW + gp0;                        \
        const float* pB = q_ + rB * ROWW + gp0;                        \
        float4 aT = *(const float4*)pT, bT = *(const float4*)(pT + 4); \
        float4 aC = *(const float4*)pC, bC = *(const float4*)(pC + 4); \
        float4 aB = *(const float4*)pB, bB = *(const float4*)(pB + 4); \
        const float* tp = ktaps + (c0 + (CI)) * 12;                    \
        float4 kA = *(const float4*)tp;                                \
        float4 kB = *(const float4*)(tp + 4);                          \
        float  k8v = tp[8];                                            \
        float k0 = kA.x * mT, k1 = kA.y * mT, k2 = kA.z * mT;          \
        float k3 = kA.w,      k4 = kB.x,      k5 = kB.y;               \
        float k6 = kB.z * mB, k7 = kB.w * mB, k8 = k8v * mB;           \
        float o0 = 0.f, o1 = 0.f, o2 = 0.f, o3 = 0.f;                  \
        float o4 = 0.f, o5 = 0.f, o6 = 0.f, o7 = 0.f;                  \
        ROWACC(aT, bT, k0, k1, k2)                                     \
        ROWACC(aC, bC, k3, k4, k5)                                     \
        ROWACC(aB, bB, k6, k7, k8)                                     \
        bv0[(CI)] = (__bf16)fmaxf(o0, 0.f);                            \
        bv1[(CI)] = (__bf16)fmaxf(o1, 0.f);                            \
        bv2[(CI)] = (__bf16)fmaxf(o2, 0.f);                            \
        bv3[(CI)] = (__bf16)fmaxf(o3, 0.f);                            \
        bv4[(CI)] = (__bf16)fmaxf(o4, 0.f);                            \
        bv5[(CI)] = (__bf16)fmaxf(o5, 0.f);                            \
        bv6[(CI)] = (__bf16)fmaxf(o6, 0.f);                            \
        bv7[(CI)] = (__bf16)fmaxf(o7, 0.f); }

        DW_CH(0) DW_CH(1) DW_CH(2) DW_CH(3)
#undef DW_CH
#undef ROWACC

        // store: vblock v = cg>>1 at slot (v ^ pg), half = cg&1
        int slotoff = (((cg >> 1) ^ pg) * 8) + ((cg & 1) * 4);
#define ST(J) *reinterpret_cast<bf16x4*>(&dwT[(pg * 8 + (J)) * 136 + slotoff]) = bv##J;
        ST(0) ST(1) ST(2) ST(3) ST(4) ST(5) ST(6) ST(7)
#undef ST
    }
    __syncthreads();
    __builtin_amdgcn_sched_barrier(0);

    // ---------------- Phase 2: 1x1 conv via MFMA (D rows = px) + epilogue ----------------
    {
        int w    = t >> 6;        // wave -> otile (8 otiles of 16 o)
        int lane = t & 63;
        int r = lane & 15;
        int g = lane >> 4;

        bf16x8 bfr[4];
        #pragma unroll
        for (int kc = 0; kc < 4; ++kc)
            bfr[kc] = *reinterpret_cast<const bf16x8*>(
                wfrag + ((size_t)(w * 4 + kc) * 64 + lane) * 8);

        f32x4 acc[8];
        #pragma unroll
        for (int pt = 0; pt < 8; ++pt) acc[pt] = (f32x4){0.f, 0.f, 0.f, 0.f};

        #pragma unroll
        for (int pt = 0; pt < 8; ++pt) {
            int px = pt * 16 + r;
            int srow = px * 136;
            int s2 = px >> 3;
            #pragma unroll
            for (int kc = 0; kc < 4; ++kc) {
                bf16x8 a = *reinterpret_cast<const bf16x8*>(
                    &dwT[srow + (((kc * 4 + g) ^ s2) * 8)]);
                acc[pt] = __builtin_amdgcn_mfma_f32_16x16x32_bf16(a, bfr[kc], acc[pt], 0, 0, 0);
            }
        }

        int o = w * 16 + r;
        float bi = conv_b[o];
        float at = att_w[b * 128 + o];
        size_t rowoff = (size_t)(b * 128 + o) * PLANE + (size_t)h * ROWW;
        const float* xrow = x + rowoff;
        float* orow = out + rowoff;
        #pragma unroll
        for (int pt = 0; pt < 8; ++pt) {
            int px = pt * 16 + g * 4;
            float4 xv = *(const float4*)(xrow + px);
            float4 ov;
            ov.x = acc[pt][0] + bi + xv.x * at;
            ov.y = acc[pt][1] + bi + xv.y * at;
            ov.z = acc[pt][2] + bi + xv.z * at;
            ov.w = acc[pt][3] + bi + xv.w * at;
            *(float4*)(orow + px) = ov;
        }
    }
}

extern "C" void kernel_launch(void* const* d_in, const int* in_sizes, int n_in,
                              void* d_out, int out_size, void* d_ws, size_t ws_size,
                              hipStream_t stream) {
    (void)in_sizes; (void)n_in; (void)out_size; (void)ws_size;
    const float* x        = (const float*)d_in[0];
    const float* altitude = (const float*)d_in[1];
    const float* W1       = (const float*)d_in[2];
    const float* W2       = (const float*)d_in[3];
    const float* conv_w   = (const float*)d_in[4];
    const float* conv_b   = (const float*)d_in[5];
    const float* ca_w1    = (const float*)d_in[6];
    const float* ca_w2    = (const float*)d_in[7];
    float* out = (float*)d_out;
    float* ws  = (float*)d_ws;

    hipLaunchKernelGGL(precompute_kernel, dim3(32), dim3(256), 0, stream,
                       altitude, W1, W2, ca_w1, ca_w2, conv_w, ws);
    hipLaunchKernelGGL(fused_kernel, dim3(1024), dim3(512), 0, stream,
                       x, conv_b, ws, out);
}

// Round 9
// 44.766 us; speedup vs baseline: 1.0895x; 1.0895x over previous
//
#include <hip/hip_runtime.h>
#include <math.h>

typedef __attribute__((ext_vector_type(8))) __bf16 bf16x8;
typedef __attribute__((ext_vector_type(4))) __bf16 bf16x4;
typedef __attribute__((ext_vector_type(4))) float f32x4;

#define PLANE 16384
#define ROWW 128

// ws float layout:
//   [0, 12288)     kern [b][c][12]  (taps 0..8 + pad, f4-aligned)
//   [12288, 13312) att  [b][128]
//   [13312, 21504) wfrag: 16384 ushorts (bf16). B-operand fragments of conv_w^T:
//                  frag[ot(8)][kc(4)][lane(64)][j(8)] = conv_w[ot*16+(lane&15)][kc*32+8*(lane>>4)+j]

__global__ __launch_bounds__(256) void precompute_kernel(
    const float* __restrict__ altitude,
    const float* __restrict__ W1,
    const float* __restrict__ W2,
    const float* __restrict__ ca_w1,
    const float* __restrict__ ca_w2,
    const float* __restrict__ conv_w,
    float* __restrict__ ws)
{
    int bid = blockIdx.x;
    int b = bid >> 2;          // image
    int q = bid & 3;           // quarter of the kern work
    int t = threadIdx.x;
    __shared__ float alt_s[128];
    __shared__ float feat_s[128];
    __shared__ float a1_s[16];

    if (t < 128) alt_s[t] = altitude[b * 128 + t];
    __syncthreads();

    if (t < 128) {
        float s = 0.f;
        const float* wrow = W1 + t * 128;
        for (int j = 0; j < 128; ++j) s += alt_s[j] * wrow[j];
        feat_s[t] = (s >= 0.f) ? s : 0.1f * s;
    } else if (t < 144 && q == 1) {
        int r = t - 128;
        float s = 0.f;
        const float* wrow = ca_w1 + r * 128;
        for (int j = 0; j < 128; ++j) s += alt_s[j] * wrow[j];
        a1_s[r] = (s >= 0.f) ? s : 0.1f * s;
    }
    __syncthreads();

    // this quarter's slice of the 1152 generated-kernel dots -> [b][c][12]
    for (int i = t; i < 288; i += 256) {
        int m = q * 288 + i;
        float s = 0.f;
        const float* wrow = W2 + m * 128;
        for (int j = 0; j < 128; ++j) s += feat_s[j] * wrow[j];
        int c = m / 9, k = m % 9;
        ws[b * 1536 + c * 12 + k] = s;
    }
    if (q == 1 && t < 128) {
        float s = 0.f;
        const float* wrow = ca_w2 + t * 16;
        for (int r = 0; r < 16; ++r) s += a1_s[r] * wrow[r];
        ws[12288 + b * 128 + t] = 1.f / (1.f + expf(-s));
    }
    if (q == 2 && t < 256) {
        int kc   = t >> 6;
        int lane = t & 63;
        int o  = b * 16 + (lane & 15);
        int cb = kc * 32 + 8 * (lane >> 4);
        bf16x8 v;
        #pragma unroll
        for (int j = 0; j < 8; ++j)
            v[j] = (__bf16)conv_w[o * 128 + cb + j];
        ushort* wf = (ushort*)(ws + 13312);
        *reinterpret_cast<bf16x8*>(wf + ((size_t)(b * 4 + kc) * 64 + lane) * 8) = v;
    }
}

// Block = 2 output rows x 128 px x 128 ch. Phase 1 reads 4 CONSECUTIVE rows
// per channel (2KB contiguous per channel) with vertical register reuse.
__global__ __launch_bounds__(512, 4) void fused_kernel(
    const float* __restrict__ x,
    const float* __restrict__ conv_b,
    const float* __restrict__ ws,
    float* __restrict__ out)
{
    const float* __restrict__ kern_w = ws;
    const float* __restrict__ att_w  = ws + 12288;
    const ushort* __restrict__ wfrag = (const ushort*)(ws + 13312);

    int bid = blockIdx.x;
    int b  = bid & 7;          // XCD swizzle: each XCD streams one batch image
    int rb = bid >> 3;         // row-pair 0..63
    int h0 = rb * 2;

    // two row-planes: dwT[row][px][c] bf16, px stride 136 ushorts;
    // c in 16 vblocks of 8; vblock v at slot (v ^ pg); read chunk ^ (px>>3).
    __shared__ __align__(16) ushort dwT[2][128 * 136];
    __shared__ __align__(16) float ktaps[128 * 12];   // [c][12] taps

    int t = threadIdx.x;
    const float* __restrict__ xb = x + (size_t)b * 128 * PLANE;

    for (int i = t; i < 384; i += 512) {
        float4 v = *(const float4*)(kern_w + b * 1536 + i * 4);
        *(float4*)(&ktaps[i * 4]) = v;
    }
    __syncthreads();

    // ---------------- Phase 1: depthwise 3x3 + ReLU (2 rows) -> dwT ----------------
    {
        int pg = t & 15;           // 8-px group (full 128-px row)
        int cg = t >> 4;           // 4-ch group, cg 0..31
        int gp0 = pg * 8;
        int c0 = cg * 4;

        float mL = (pg > 0)  ? 1.f : 0.f;
        float mR = (pg < 15) ? 1.f : 0.f;
        float mTop = (rb > 0)  ? 1.f : 0.f;   // staged row 0 validity
        float mBot = (rb < 63) ? 1.f : 0.f;   // staged row 3 validity
        int r0 = (rb > 0)  ? h0 - 1 : h0;     // clamped (tap-masked anyway)
        int r3 = (rb < 63) ? h0 + 2 : h0;

        bf16x4 bv[2][8];   // [row][pxj] -> 4 bf16 along c; literal indices only

#define NEIGH(A, B, LV, RV) \
        float LV = __shfl_up((B).w, 1) * mL; \
        float RV = __shfl_down((A).x, 1) * mR;

#define ROWACC(A, B, LV, RV, KL, KC, KR) {                                \
        o0 = fmaf((KL), LV,    fmaf((KC), (A).x, fmaf((KR), (A).y, o0))); \
        o1 = fmaf((KL), (A).x, fmaf((KC), (A).y, fmaf((KR), (A).z, o1))); \
        o2 = fmaf((KL), (A).y, fmaf((KC), (A).z, fmaf((KR), (A).w, o2))); \
        o3 = fmaf((KL), (A).z, fmaf((KC), (A).w, fmaf((KR), (B).x, o3))); \
        o4 = fmaf((KL), (A).w, fmaf((KC), (B).x, fmaf((KR), (B).y, o4))); \
        o5 = fmaf((KL), (B).x, fmaf((KC), (B).y, fmaf((KR), (B).z, o5))); \
        o6 = fmaf((KL), (B).y, fmaf((KC), (B).z, fmaf((KR), (B).w, o6))); \
        o7 = fmaf((KL), (B).z, fmaf((KC), (B).w, fmaf((KR), RV,    o7))); }

#define DW_CH(CI) {                                                    \
        const float* q_ = xb + (size_t)(c0 + (CI)) * PLANE;            \
        const float* p0_ = q_ + r0 * ROWW + gp0;                       \
        const float* p1_ = q_ + h0 * ROWW + gp0;                       \
        const float* p2_ = q_ + (h0 + 1) * ROWW + gp0;                 \
        const float* p3_ = q_ + r3 * ROWW + gp0;                       \
        float4 a0 = *(const float4*)p0_, b0 = *(const float4*)(p0_ + 4); \
        float4 a1 = *(const float4*)p1_, b1 = *(const float4*)(p1_ + 4); \
        float4 a2 = *(const float4*)p2_, b2 = *(const float4*)(p2_ + 4); \
        float4 a3 = *(const float4*)p3_, b3 = *(const float4*)(p3_ + 4); \
        NEIGH(a0, b0, l0, rr0) NEIGH(a1, b1, l1, rr1)                  \
        NEIGH(a2, b2, l2, rr2) NEIGH(a3, b3, l3, rr3)                  \
        const float* tp = ktaps + (c0 + (CI)) * 12;                    \
        float4 kA = *(const float4*)tp;                                \
        float4 kB = *(const float4*)(tp + 4);                          \
        float  k8v = tp[8];                                            \
        {   /* output row 0: staged 0,1,2 ; top taps masked */         \
            float o0 = 0.f, o1 = 0.f, o2 = 0.f, o3 = 0.f;              \
            float o4 = 0.f, o5 = 0.f, o6 = 0.f, o7 = 0.f;              \
            ROWACC(a0, b0, l0, rr0, kA.x * mTop, kA.y * mTop, kA.z * mTop) \
            ROWACC(a1, b1, l1, rr1, kA.w, kB.x, kB.y)                  \
            ROWACC(a2, b2, l2, rr2, kB.z, kB.w, k8v)                   \
            bv[0][0][(CI)] = (__bf16)fmaxf(o0, 0.f);                   \
            bv[0][1][(CI)] = (__bf16)fmaxf(o1, 0.f);                   \
            bv[0][2][(CI)] = (__bf16)fmaxf(o2, 0.f);                   \
            bv[0][3][(CI)] = (__bf16)fmaxf(o3, 0.f);                   \
            bv[0][4][(CI)] = (__bf16)fmaxf(o4, 0.f);                   \
            bv[0][5][(CI)] = (__bf16)fmaxf(o5, 0.f);                   \
            bv[0][6][(CI)] = (__bf16)fmaxf(o6, 0.f);                   \
            bv[0][7][(CI)] = (__bf16)fmaxf(o7, 0.f);                   \
        }                                                              \
        {   /* output row 1: staged 1,2,3 ; bottom taps masked */      \
            float o0 = 0.f, o1 = 0.f, o2 = 0.f, o3 = 0.f;              \
            float o4 = 0.f, o5 = 0.f, o6 = 0.f, o7 = 0.f;              \
            ROWACC(a1, b1, l1, rr1, kA.x, kA.y, kA.z)                  \
            ROWACC(a2, b2, l2, rr2, kA.w, kB.x, kB.y)                  \
            ROWACC(a3, b3, l3, rr3, kB.z * mBot, kB.w * mBot, k8v * mBot) \
            bv[1][0][(CI)] = (__bf16)fmaxf(o0, 0.f);                   \
            bv[1][1][(CI)] = (__bf16)fmaxf(o1, 0.f);                   \
            bv[1][2][(CI)] = (__bf16)fmaxf(o2, 0.f);                   \
            bv[1][3][(CI)] = (__bf16)fmaxf(o3, 0.f);                   \
            bv[1][4][(CI)] = (__bf16)fmaxf(o4, 0.f);                   \
            bv[1][5][(CI)] = (__bf16)fmaxf(o5, 0.f);                   \
            bv[1][6][(CI)] = (__bf16)fmaxf(o6, 0.f);                   \
            bv[1][7][(CI)] = (__bf16)fmaxf(o7, 0.f);                   \
        } }

        DW_CH(0) DW_CH(1) DW_CH(2) DW_CH(3)
#undef DW_CH
#undef ROWACC
#undef NEIGH

        // store: vblock v = cg>>1 at slot (v ^ pg), half = cg&1
        int slotoff = (((cg >> 1) ^ pg) * 8) + ((cg & 1) * 4);
#define ST(RW, J) *reinterpret_cast<bf16x4*>(&dwT[RW][(pg * 8 + (J)) * 136 + slotoff]) = bv[RW][J];
        ST(0,0) ST(0,1) ST(0,2) ST(0,3) ST(0,4) ST(0,5) ST(0,6) ST(0,7)
        ST(1,0) ST(1,1) ST(1,2) ST(1,3) ST(1,4) ST(1,5) ST(1,6) ST(1,7)
#undef ST
    }
    __syncthreads();
    __builtin_amdgcn_sched_barrier(0);

    // ---------------- Phase 2: 1x1 conv via MFMA (D rows = px), 2 rows ----------------
    {
        int w    = t >> 6;        // wave -> otile (8 otiles of 16 o)
        int lane = t & 63;
        int r = lane & 15;
        int g = lane >> 4;

        bf16x8 bfr[4];
        #pragma unroll
        for (int kc = 0; kc < 4; ++kc)
            bfr[kc] = *reinterpret_cast<const bf16x8*>(
                wfrag + ((size_t)(w * 4 + kc) * 64 + lane) * 8);

        int o = w * 16 + r;
        float bi = conv_b[o];
        float at = att_w[b * 128 + o];

        #pragma unroll 1
        for (int r2 = 0; r2 < 2; ++r2) {
            const ushort* plane = dwT[r2];
            size_t rowoff = (size_t)(b * 128 + o) * PLANE + (size_t)(h0 + r2) * ROWW;
            const float* xrow = x + rowoff;
            float* orow = out + rowoff;

            // prefetch residual x (8 independent float4s hide under MFMA)
            float4 xv[8];
            #pragma unroll
            for (int pt = 0; pt < 8; ++pt)
                xv[pt] = *(const float4*)(xrow + pt * 16 + g * 4);

            f32x4 acc[8];
            #pragma unroll
            for (int pt = 0; pt < 8; ++pt) acc[pt] = (f32x4){0.f, 0.f, 0.f, 0.f};

            #pragma unroll
            for (int pt = 0; pt < 8; ++pt) {
                int px = pt * 16 + r;
                int srow = px * 136;
                int s2 = px >> 3;
                #pragma unroll
                for (int kc = 0; kc < 4; ++kc) {
                    bf16x8 a = *reinterpret_cast<const bf16x8*>(
                        &plane[srow + (((kc * 4 + g) ^ s2) * 8)]);
                    acc[pt] = __builtin_amdgcn_mfma_f32_16x16x32_bf16(a, bfr[kc], acc[pt], 0, 0, 0);
                }
            }

            #pragma unroll
            for (int pt = 0; pt < 8; ++pt) {
                int px = pt * 16 + g * 4;
                float4 ov;
                ov.x = acc[pt][0] + bi + xv[pt].x * at;
                ov.y = acc[pt][1] + bi + xv[pt].y * at;
                ov.z = acc[pt][2] + bi + xv[pt].z * at;
                ov.w = acc[pt][3] + bi + xv[pt].w * at;
                *(float4*)(orow + px) = ov;
            }
        }
    }
}

extern "C" void kernel_launch(void* const* d_in, const int* in_sizes, int n_in,
                              void* d_out, int out_size, void* d_ws, size_t ws_size,
                              hipStream_t stream) {
    (void)in_sizes; (void)n_in; (void)out_size; (void)ws_size;
    const float* x        = (const float*)d_in[0];
    const float* altitude = (const float*)d_in[1];
    const float* W1       = (const float*)d_in[2];
    const float* W2       = (const float*)d_in[3];
    const float* conv_w   = (const float*)d_in[4];
    const float* conv_b   = (const float*)d_in[5];
    const float* ca_w1    = (const float*)d_in[6];
    const float* ca_w2    = (const float*)d_in[7];
    float* out = (float*)d_out;
    float* ws  = (float*)d_ws;

    hipLaunchKernelGGL(precompute_kernel, dim3(32), dim3(256), 0, stream,
                       altitude, W1, W2, ca_w1, ca_w2, conv_w, ws);
    hipLaunchKernelGGL(fused_kernel, dim3(512), dim3(512), 0, stream,
                       x, conv_b, ws, out);
}